// Round 1
// baseline (569.142 us; speedup 1.0000x reference)
//
#include <hip/hip_runtime.h>
#include <math.h>

#define NB 64
#define KK 512
#define ND 1024
#define NH 32
#define G3 96   // 3*H
#define DPE 32

// ---------------- kernel 1: x-projection (pe @ kernel + bias0), both dirs ----
__global__ __launch_bounds__(192) void xproj_kernel(
    const float* __restrict__ kF, const float* __restrict__ bF,
    const float* __restrict__ kB, const float* __restrict__ bB,
    float* __restrict__ xproj) {
  int k = blockIdx.x;
  int t = threadIdx.x;
  __shared__ float pe[DPE];
  if (t < DPE) {
    int j = t >> 1;
    float dv = expf((float)j * -0.57564627324851147f);  // -ln(10000)/16
    float arg = (float)k * dv;
    pe[t] = (t & 1) ? cosf(arg) : sinf(arg);
  }
  __syncthreads();
  int dir = t / G3;
  int c = t - dir * G3;
  const float* kern = dir ? kB : kF;
  const float* bias = dir ? bB : bF;
  float acc = bias[c];
#pragma unroll
  for (int i = 0; i < DPE; ++i) acc = fmaf(pe[i], kern[i * G3 + c], acc);
  xproj[dir * (KK * G3) + k * G3 + c] = acc;
}

// ---------------- kernel 2: sequential GRU per (b, dir) ---------------------
__global__ __launch_bounds__(128) void gru_kernel(
    const float* __restrict__ rkF, const float* __restrict__ rkB,
    const float* __restrict__ bF, const float* __restrict__ bB,
    const float* __restrict__ lw, const int* __restrict__ lengths,
    const float* __restrict__ xproj, float* __restrict__ scoreW) {
  int bid = blockIdx.x;
  int b = bid >> 1, dir = bid & 1;
  int c = threadIdx.x;
  const float* rk_g = dir ? rkB : rkF;
  const float* bias = dir ? bB : bF;
  const float* xp_g = xproj + dir * (KK * G3);
  int len = lengths[b];

  __shared__ __align__(16) float h[NH];
  __shared__ float preA[G3];
  __shared__ float preB[NH];

  float rk[DPE];
  float b1c = 0.f, lwc = 0.f;
  if (c < G3) {
#pragma unroll
    for (int i = 0; i < DPE; ++i) rk[i] = rk_g[i * G3 + c];
    b1c = bias[G3 + c];  // recurrent bias row
  }
  if (c < NH) { h[c] = 0.f; lwc = lw[dir * NH + c]; }
  __syncthreads();

  float xp_next = 0.f;
  if (c < G3) xp_next = xp_g[(dir ? (len - 1) : 0) * G3 + c];

  for (int s = 0; s < len; ++s) {
    int p = dir ? (len - 1 - s) : s;
    float xp = xp_next;
    if (c < G3 && s + 1 < len) {
      int pn = dir ? (len - 2 - s) : (s + 1);
      xp_next = xp_g[pn * G3 + c];
    }
    if (c < G3) {
      const float4* h4 = reinterpret_cast<const float4*>(h);
      float a0 = 0.f, a1 = 0.f, a2 = 0.f, a3 = 0.f;
#pragma unroll
      for (int q = 0; q < 8; ++q) {
        float4 hv = h4[q];
        a0 = fmaf(hv.x, rk[4 * q + 0], a0);
        a1 = fmaf(hv.y, rk[4 * q + 1], a1);
        a2 = fmaf(hv.z, rk[4 * q + 2], a2);
        a3 = fmaf(hv.w, rk[4 * q + 3], a3);
      }
      float hp = (a0 + a1) + (a2 + a3) + b1c;
      if (c < 2 * NH) {
        preA[c] = xp + hp;          // z,r pre-activations
      } else {
        preA[c] = xp;               // xh
        preB[c - 2 * NH] = hp;      // hh (bias inside, multiplied by r)
      }
    }
    __syncthreads();
    if (c < NH) {
      float z = 1.f / (1.f + expf(-preA[c]));
      float r = 1.f / (1.f + expf(-preA[NH + c]));
      float hc = tanhf(preA[2 * NH + c] + r * preB[c]);
      float hold = h[c];
      float hn = z * hold + (1.f - z) * hc;
      h[c] = hn;
      float sc = hn * lwc;
#pragma unroll
      for (int m = 16; m >= 1; m >>= 1) sc += __shfl_xor(sc, m, 32);
      if (c == 0) scoreW[(dir * NB + b) * KK + p] = sc;
    }
    __syncthreads();
  }
}

// ---------------- kernel 3: softmax over K per batch ------------------------
__global__ __launch_bounds__(256) void softmax_kernel(
    const int* __restrict__ lengths, const float* __restrict__ scoreW,
    float* __restrict__ wts, float* __restrict__ outW) {
  int b = blockIdx.x;
  int t = threadIdx.x;
  int len = lengths[b];
  const float* sf = scoreW + b * KK;
  const float* sb = scoreW + (NB + b) * KK;
  int k0 = t, k1 = t + 256;
  float s0 = -10000.f, s1 = -10000.f;
  if (k0 < len) s0 = sf[k0] + sb[k0];
  if (k1 < len) s1 = sf[k1] + sb[k1];
  float mx = fmaxf(s0, s1);
#pragma unroll
  for (int m = 32; m >= 1; m >>= 1) mx = fmaxf(mx, __shfl_xor(mx, m, 64));
  __shared__ float redm[4];
  __shared__ float reds[4];
  int wid = t >> 6, lane = t & 63;
  if (lane == 0) redm[wid] = mx;
  __syncthreads();
  mx = fmaxf(fmaxf(redm[0], redm[1]), fmaxf(redm[2], redm[3]));
  float e0 = expf((s0 - mx) * 10.f);  // padded -> exp(~-1e5) == 0 exactly
  float e1 = expf((s1 - mx) * 10.f);
  float sum = e0 + e1;
#pragma unroll
  for (int m = 32; m >= 1; m >>= 1) sum += __shfl_xor(sum, m, 64);
  if (lane == 0) reds[wid] = sum;
  __syncthreads();
  sum = (reds[0] + reds[1]) + (reds[2] + reds[3]);
  float inv = 1.f / sum;
  float w0 = e0 * inv, w1 = e1 * inv;
  wts[b * KK + k0] = w0;
  wts[b * KK + k1] = w1;
  outW[b * KK + k0] = w0;
  outW[b * KK + k1] = w1;
}

// ---------------- kernel 4: per-(b,d) descending sort + weighted pool -------
// grid: 64 b * 64 dtiles (16 cols each). Each wave sorts 4 columns:
// 512 elems = 64 lanes x 8 regs, s = 8*lane + r, bitonic ascending.
__global__ __launch_bounds__(256) void sortpool_kernel(
    const float* __restrict__ feat, const int* __restrict__ lengths,
    const float* __restrict__ wts, float* __restrict__ outP) {
  __shared__ float tile[KK * 16];   // 32 KB, rotation-swizzled
  __shared__ float wperm[KK];       // transposed weight layout
  int bid = blockIdx.x;
  int b = bid >> 6;
  int dt = bid & 63;
  int d0 = dt * 16;
  int t = threadIdx.x;
  int len = lengths[b];

  // stage weights (transposed: w[i] at (i&7)*64 + (i>>3) -> conflict-free read)
#pragma unroll
  for (int it = 0; it < 2; ++it) {
    int i = it * 256 + t;
    wperm[(i & 7) * 64 + (i >> 3)] = wts[b * KK + i];
  }
  // stage features: coalesced float4 reads, swizzled LDS writes
  const float4* g = reinterpret_cast<const float4*>(feat + (size_t)b * KK * ND + d0);
  int c4 = t & 3, kb = t >> 2;  // 4 float4-groups x 64 k-rows per iter
#pragma unroll
  for (int it = 0; it < 8; ++it) {
    int k = it * 64 + kb;
    float4 v = g[(size_t)k * 256 + c4];
    if (k >= len) { v.x = -10000.f; v.y = -10000.f; v.z = -10000.f; v.w = -10000.f; }
    int base = k * 16;
    int rot = (k >> 3) + (k & 7);
    tile[base + ((c4 * 4 + 0 + rot) & 15)] = v.x;
    tile[base + ((c4 * 4 + 1 + rot) & 15)] = v.y;
    tile[base + ((c4 * 4 + 2 + rot) & 15)] = v.z;
    tile[base + ((c4 * 4 + 3 + rot) & 15)] = v.w;
  }
  __syncthreads();

  int wv = t >> 6, l = t & 63;
  for (int cc = 0; cc < 4; ++cc) {
    int d = wv * 4 + cc;
    float v[8];
#pragma unroll
    for (int r = 0; r < 8; ++r) {
      int k = 8 * l + r;
      v[r] = tile[k * 16 + ((d + l + r) & 15)];
    }
    // bitonic sort ascending on s = 8*l + r
#pragma unroll
    for (int kk = 1; kk <= 9; ++kk) {
#pragma unroll
      for (int j = kk - 1; j >= 0; --j) {
        if (j >= 3) {
          int m = 1 << (j - 3);
          unsigned up = (((unsigned)l >> (kk - 3)) & 1u) ^ 1u;
          unsigned hb = ((unsigned)l >> (j - 3)) & 1u;
          bool keepmin = (up ^ hb) != 0u;
#pragma unroll
          for (int r = 0; r < 8; ++r) {
            float p = __shfl_xor(v[r], m, 64);
            v[r] = keepmin ? fminf(v[r], p) : fmaxf(v[r], p);
          }
        } else {
          int mb = 1 << j;
#pragma unroll
          for (int r = 0; r < 8; ++r) {
            if (!(r & mb)) {
              int r2 = r | mb;
              bool up = ((((l << 3) + r) >> kk) & 1) == 0;
              float lo = fminf(v[r], v[r2]);
              float hi = fmaxf(v[r], v[r2]);
              v[r] = up ? lo : hi;
              v[r2] = up ? hi : lo;
            }
          }
        }
      }
    }
    // weighted sum: ascending rank s -> descending rank jd = 511 - s
    float acc = 0.f;
#pragma unroll
    for (int r = 0; r < 8; ++r) {
      int jd = 511 - (8 * l + r);
      if (jd < len) acc = fmaf(v[r], wperm[(jd & 7) * 64 + (jd >> 3)], acc);
    }
#pragma unroll
    for (int m = 32; m >= 1; m >>= 1) acc += __shfl_xor(acc, m, 64);
    if (l == 0) outP[(size_t)b * ND + d0 + d] = acc;
  }
}

extern "C" void kernel_launch(void* const* d_in, const int* in_sizes, int n_in,
                              void* d_out, int out_size, void* d_ws, size_t ws_size,
                              hipStream_t stream) {
  const float* feat   = (const float*)d_in[0];
  const int*   lengths= (const int*)d_in[1];
  const float* kF     = (const float*)d_in[2];
  const float* rkF    = (const float*)d_in[3];
  const float* bF     = (const float*)d_in[4];
  const float* kB     = (const float*)d_in[5];
  const float* rkB    = (const float*)d_in[6];
  const float* bB     = (const float*)d_in[7];
  const float* lw     = (const float*)d_in[8];

  float* outP = (float*)d_out;                 // pooled [64,1024]
  float* outW = (float*)d_out + NB * ND;       // weights [64,512]

  float* ws     = (float*)d_ws;
  float* xproj  = ws;                          // [2][512][96]
  float* scoreW = ws + 2 * KK * G3;            // [2][64][512]
  float* wts    = scoreW + 2 * NB * KK;        // [64][512]

  xproj_kernel<<<KK, 192, 0, stream>>>(kF, bF, kB, bB, xproj);
  gru_kernel<<<NB * 2, 128, 0, stream>>>(rkF, rkB, bF, bB, lw, lengths, xproj, scoreW);
  softmax_kernel<<<NB, 256, 0, stream>>>(lengths, scoreW, wts, outW);
  sortpool_kernel<<<NB * 64, 256, 0, stream>>>(feat, lengths, wts, outP);
}

// Round 2
// 422.455 us; speedup vs baseline: 1.3472x; 1.3472x over previous
//
#include <hip/hip_runtime.h>
#include <math.h>

#define NB 64
#define KK 512
#define ND 1024
#define NH 32
#define G3 96   // 3*H
#define DPE 32

// ---------------- kernel 1: x-projection (pe @ kernel + bias0), both dirs ----
__global__ __launch_bounds__(192) void xproj_kernel(
    const float* __restrict__ kF, const float* __restrict__ bF,
    const float* __restrict__ kB, const float* __restrict__ bB,
    float* __restrict__ xproj) {
  int k = blockIdx.x;
  int t = threadIdx.x;
  __shared__ float pe[DPE];
  if (t < DPE) {
    int j = t >> 1;
    float dv = expf((float)j * -0.57564627324851147f);  // -ln(10000)/16
    float arg = (float)k * dv;
    pe[t] = (t & 1) ? cosf(arg) : sinf(arg);
  }
  __syncthreads();
  int dir = t / G3;
  int c = t - dir * G3;
  const float* kern = dir ? kB : kF;
  const float* bias = dir ? bB : bF;
  float acc = bias[c];
#pragma unroll
  for (int i = 0; i < DPE; ++i) acc = fmaf(pe[i], kern[i * G3 + c], acc);
  xproj[dir * (KK * G3) + k * G3 + c] = acc;
}

// ---------------- kernel 2: sequential GRU, 1 wave per (b,dir) --------------
// lane l<32: z-column l; lane l>=32: r-column l-32; all lanes: h-column (l&31).
// h broadcast via v_readlane (SGPRs), no LDS, no barriers, no in-loop reduce.
__global__ __launch_bounds__(64) void gru2_kernel(
    const float* __restrict__ rkF, const float* __restrict__ rkB,
    const float* __restrict__ bF, const float* __restrict__ bB,
    const int* __restrict__ lengths, const float* __restrict__ xproj,
    float* __restrict__ hbuf) {
  int bid = blockIdx.x;
  int b = bid >> 1, dir = bid & 1;
  int l = threadIdx.x;
  int c = l & 31;
  const float* rk_g = dir ? rkB : rkF;
  const float* bias = dir ? bB : bF;
  const float* xp_g = xproj + dir * (KK * G3);
  int len = lengths[b];

  float rk_zr[32], rk_h[32];
#pragma unroll
  for (int i = 0; i < 32; ++i) {
    rk_zr[i] = rk_g[i * G3 + l];       // z cols for l<32, r cols for l>=32
    rk_h[i]  = rk_g[i * G3 + 64 + c];  // h cols (replicated across halves)
  }
  float b_zr = bias[G3 + l];
  float b_h  = bias[G3 + 64 + c];

  // hbuf layout: [b][k][dir*32 + c]
  float* hstore = hbuf + (size_t)b * KK * 64 + dir * 32 + c;

  int pstep = dir ? -G3 : G3;
  const float* xp0 = xp_g + (size_t)(dir ? (len - 1) : 0) * G3;
  float xzr0 = xp0[l], xh0 = xp0[64 + c];
  float xzr1 = 0.f, xh1 = 0.f;
  if (len > 1) { const float* x1 = xp0 + pstep; xzr1 = x1[l]; xh1 = x1[64 + c]; }
  const float* xpp = xp0 + 2 * pstep;

  float hval = 0.f;
  int p = dir ? (len - 1) : 0;
  int pinc = dir ? -1 : 1;

  for (int s = 0; s < len; ++s) {
    float az0 = 0.f, az1 = 0.f, az2 = 0.f, az3 = 0.f;
    float ah0 = 0.f, ah1 = 0.f, ah2 = 0.f, ah3 = 0.f;
#pragma unroll
    for (int i = 0; i < 32; i += 4) {
      float h0 = __uint_as_float(__builtin_amdgcn_readlane(__float_as_uint(hval), i));
      float h1 = __uint_as_float(__builtin_amdgcn_readlane(__float_as_uint(hval), i + 1));
      float h2 = __uint_as_float(__builtin_amdgcn_readlane(__float_as_uint(hval), i + 2));
      float h3 = __uint_as_float(__builtin_amdgcn_readlane(__float_as_uint(hval), i + 3));
      az0 = fmaf(h0, rk_zr[i + 0], az0);  ah0 = fmaf(h0, rk_h[i + 0], ah0);
      az1 = fmaf(h1, rk_zr[i + 1], az1);  ah1 = fmaf(h1, rk_h[i + 1], ah1);
      az2 = fmaf(h2, rk_zr[i + 2], az2);  ah2 = fmaf(h2, rk_h[i + 2], ah2);
      az3 = fmaf(h3, rk_zr[i + 3], az3);  ah3 = fmaf(h3, rk_h[i + 3], ah3);
    }
    float zr_pre = ((az0 + az1) + (az2 + az3)) + b_zr + xzr0;
    float hh     = ((ah0 + ah1) + (ah2 + ah3)) + b_h;
    float sig = 1.f / (1.f + __expf(-zr_pre));        // z (l<32) or r (l>=32)
    float other = __shfl_xor(sig, 32, 64);
    float z = (l < 32) ? sig : other;
    float r = (l < 32) ? other : sig;
    float pre = fmaf(r, hh, xh0);
    float e2 = __expf(2.f * pre);                     // tanh = 1 - 2/(e^{2x}+1)
    float hc = 1.f - 2.f / (e2 + 1.f);
    hval = fmaf(z, hval - hc, hc);
    if (l < 32) hstore[(size_t)p * 64] = hval;
    xzr0 = xzr1; xh0 = xh1;
    if (s + 2 < len) { xzr1 = xpp[l]; xh1 = xpp[64 + c]; xpp += pstep; }
    p += pinc;
  }
}

// ---------------- kernel 3: score (h . lw) + softmax over K per batch -------
__global__ __launch_bounds__(256) void softscore_kernel(
    const int* __restrict__ lengths, const float* __restrict__ hbuf,
    const float* __restrict__ lw, float* __restrict__ wts,
    float* __restrict__ outW) {
  int b = blockIdx.x;
  int t = threadIdx.x;
  int len = lengths[b];
  __shared__ float lwS[64];
  if (t < 64) lwS[t] = lw[t];
  __syncthreads();
  const float* hb = hbuf + (size_t)b * KK * 64;

  int k0 = t, k1 = t + 256;
  float s0 = -10000.f, s1 = -10000.f;
  if (k0 < len) {
    const float4* h4 = reinterpret_cast<const float4*>(hb + (size_t)k0 * 64);
    float acc = 0.f;
#pragma unroll
    for (int q = 0; q < 16; ++q) {
      float4 v = h4[q];
      acc = fmaf(v.x, lwS[4 * q + 0], acc);
      acc = fmaf(v.y, lwS[4 * q + 1], acc);
      acc = fmaf(v.z, lwS[4 * q + 2], acc);
      acc = fmaf(v.w, lwS[4 * q + 3], acc);
    }
    s0 = acc;
  }
  if (k1 < len) {
    const float4* h4 = reinterpret_cast<const float4*>(hb + (size_t)k1 * 64);
    float acc = 0.f;
#pragma unroll
    for (int q = 0; q < 16; ++q) {
      float4 v = h4[q];
      acc = fmaf(v.x, lwS[4 * q + 0], acc);
      acc = fmaf(v.y, lwS[4 * q + 1], acc);
      acc = fmaf(v.z, lwS[4 * q + 2], acc);
      acc = fmaf(v.w, lwS[4 * q + 3], acc);
    }
    s1 = acc;
  }

  float mx = fmaxf(s0, s1);
#pragma unroll
  for (int m = 32; m >= 1; m >>= 1) mx = fmaxf(mx, __shfl_xor(mx, m, 64));
  __shared__ float redm[4];
  __shared__ float reds[4];
  int wid = t >> 6, lane = t & 63;
  if (lane == 0) redm[wid] = mx;
  __syncthreads();
  mx = fmaxf(fmaxf(redm[0], redm[1]), fmaxf(redm[2], redm[3]));
  float e0 = expf((s0 - mx) * 10.f);  // padded -> exp(~-1e5) == 0 exactly
  float e1 = expf((s1 - mx) * 10.f);
  float sum = e0 + e1;
#pragma unroll
  for (int m = 32; m >= 1; m >>= 1) sum += __shfl_xor(sum, m, 64);
  if (lane == 0) reds[wid] = sum;
  __syncthreads();
  sum = (reds[0] + reds[1]) + (reds[2] + reds[3]);
  float inv = 1.f / sum;
  float w0 = e0 * inv, w1 = e1 * inv;
  wts[b * KK + k0] = w0;
  wts[b * KK + k1] = w1;
  outW[b * KK + k0] = w0;
  outW[b * KK + k1] = w1;
}

// ---------------- kernel 4: per-(b,d) descending sort + weighted pool -------
// grid: 64 b * 64 dtiles (16 cols each). Each wave sorts 4 columns:
// 512 elems = 64 lanes x 8 regs, s = 8*lane + r, bitonic ascending.
__global__ __launch_bounds__(256) void sortpool_kernel(
    const float* __restrict__ feat, const int* __restrict__ lengths,
    const float* __restrict__ wts, float* __restrict__ outP) {
  __shared__ float tile[KK * 16];   // 32 KB, rotation-swizzled
  __shared__ float wperm[KK];       // transposed weight layout
  int bid = blockIdx.x;
  int b = bid >> 6;
  int dt = bid & 63;
  int d0 = dt * 16;
  int t = threadIdx.x;
  int len = lengths[b];

  // stage weights (transposed: w[i] at (i&7)*64 + (i>>3) -> conflict-free read)
#pragma unroll
  for (int it = 0; it < 2; ++it) {
    int i = it * 256 + t;
    wperm[(i & 7) * 64 + (i >> 3)] = wts[b * KK + i];
  }
  // stage features: coalesced float4 reads, swizzled LDS writes
  const float4* g = reinterpret_cast<const float4*>(feat + (size_t)b * KK * ND + d0);
  int c4 = t & 3, kb = t >> 2;  // 4 float4-groups x 64 k-rows per iter
#pragma unroll
  for (int it = 0; it < 8; ++it) {
    int k = it * 64 + kb;
    float4 v = g[(size_t)k * 256 + c4];
    if (k >= len) { v.x = -10000.f; v.y = -10000.f; v.z = -10000.f; v.w = -10000.f; }
    int base = k * 16;
    int rot = (k >> 3) + (k & 7);
    tile[base + ((c4 * 4 + 0 + rot) & 15)] = v.x;
    tile[base + ((c4 * 4 + 1 + rot) & 15)] = v.y;
    tile[base + ((c4 * 4 + 2 + rot) & 15)] = v.z;
    tile[base + ((c4 * 4 + 3 + rot) & 15)] = v.w;
  }
  __syncthreads();

  int wv = t >> 6, l = t & 63;
  for (int cc = 0; cc < 4; ++cc) {
    int d = wv * 4 + cc;
    float v[8];
#pragma unroll
    for (int r = 0; r < 8; ++r) {
      int k = 8 * l + r;
      v[r] = tile[k * 16 + ((d + l + r) & 15)];
    }
    // bitonic sort ascending on s = 8*l + r
#pragma unroll
    for (int kk = 1; kk <= 9; ++kk) {
#pragma unroll
      for (int j = kk - 1; j >= 0; --j) {
        if (j >= 3) {
          int m = 1 << (j - 3);
          unsigned up = (((unsigned)l >> (kk - 3)) & 1u) ^ 1u;
          unsigned hb = ((unsigned)l >> (j - 3)) & 1u;
          bool keepmin = (up ^ hb) != 0u;
#pragma unroll
          for (int r = 0; r < 8; ++r) {
            float p = __shfl_xor(v[r], m, 64);
            v[r] = keepmin ? fminf(v[r], p) : fmaxf(v[r], p);
          }
        } else {
          int mb = 1 << j;
#pragma unroll
          for (int r = 0; r < 8; ++r) {
            if (!(r & mb)) {
              int r2 = r | mb;
              bool up = ((((l << 3) + r) >> kk) & 1) == 0;
              float lo = fminf(v[r], v[r2]);
              float hi = fmaxf(v[r], v[r2]);
              v[r] = up ? lo : hi;
              v[r2] = up ? hi : lo;
            }
          }
        }
      }
    }
    // weighted sum: ascending rank s -> descending rank jd = 511 - s
    float acc = 0.f;
#pragma unroll
    for (int r = 0; r < 8; ++r) {
      int jd = 511 - (8 * l + r);
      if (jd < len) acc = fmaf(v[r], wperm[(jd & 7) * 64 + (jd >> 3)], acc);
    }
#pragma unroll
    for (int m = 32; m >= 1; m >>= 1) acc += __shfl_xor(acc, m, 64);
    if (l == 0) outP[(size_t)b * ND + d0 + d] = acc;
  }
}

extern "C" void kernel_launch(void* const* d_in, const int* in_sizes, int n_in,
                              void* d_out, int out_size, void* d_ws, size_t ws_size,
                              hipStream_t stream) {
  const float* feat    = (const float*)d_in[0];
  const int*   lengths = (const int*)d_in[1];
  const float* kF      = (const float*)d_in[2];
  const float* rkF     = (const float*)d_in[3];
  const float* bF      = (const float*)d_in[4];
  const float* kB      = (const float*)d_in[5];
  const float* rkB     = (const float*)d_in[6];
  const float* bB      = (const float*)d_in[7];
  const float* lw      = (const float*)d_in[8];

  float* outP = (float*)d_out;                 // pooled [64,1024]
  float* outW = (float*)d_out + NB * ND;       // weights [64,512]

  float* ws    = (float*)d_ws;
  float* xproj = ws;                           // [2][512][96]
  float* hbuf  = ws + 2 * KK * G3;             // [64][512][64]  (fwd32|bwd32)
  float* wts   = hbuf + (size_t)NB * KK * 64;  // [64][512]

  xproj_kernel<<<KK, 192, 0, stream>>>(kF, bF, kB, bB, xproj);
  gru2_kernel<<<NB * 2, 64, 0, stream>>>(rkF, rkB, bF, bB, lengths, xproj, hbuf);
  softscore_kernel<<<NB, 256, 0, stream>>>(lengths, hbuf, lw, wts, outW);
  sortpool_kernel<<<NB * 64, 256, 0, stream>>>(feat, lengths, wts, outP);
}

// Round 3
// 400.225 us; speedup vs baseline: 1.4221x; 1.0555x over previous
//
#include <hip/hip_runtime.h>
#include <math.h>

#define NB 64
#define KK 512
#define ND 1024
#define NH 32
#define G3 96   // 3*H
#define DPE 32

typedef float v2f __attribute__((ext_vector_type(2)));

// ---------------- kernel 1: x-projection (pe @ kernel + bias0 + zr-part of
// bias1 folded), both dirs ----------------------------------------------------
__global__ __launch_bounds__(192) void xproj_kernel(
    const float* __restrict__ kF, const float* __restrict__ bF,
    const float* __restrict__ kB, const float* __restrict__ bB,
    float* __restrict__ xproj) {
  int k = blockIdx.x;
  int t = threadIdx.x;
  __shared__ float pe[DPE];
  if (t < DPE) {
    int j = t >> 1;
    float dv = expf((float)j * -0.57564627324851147f);  // -ln(10000)/16
    float arg = (float)k * dv;
    pe[t] = (t & 1) ? cosf(arg) : sinf(arg);
  }
  __syncthreads();
  int dir = t / G3;
  int c = t - dir * G3;
  const float* kern = dir ? kB : kF;
  const float* bias = dir ? bB : bF;
  float acc = bias[c] + (c < 64 ? bias[G3 + c] : 0.f);  // fold recurrent zr bias
#pragma unroll
  for (int i = 0; i < DPE; ++i) acc = fmaf(pe[i], kern[i * G3 + c], acc);
  xproj[dir * (KK * G3) + k * G3 + c] = acc;
}

// ---------------- kernel 2: sequential GRU, 1 wave per (b,dir) --------------
// One half-wave computes the z-dot, the other the r-dot (assignment chosen at
// init to match permlane32_swap's return order); all lanes compute the h-dot
// for column c = l&31. No LDS, no barriers, no divisions.
__global__ __launch_bounds__(64) void gru3_kernel(
    const float* __restrict__ rkF, const float* __restrict__ rkB,
    const float* __restrict__ bF, const float* __restrict__ bB,
    const int* __restrict__ lengths, const float* __restrict__ xproj,
    float* __restrict__ hbuf) {
  int bid = blockIdx.x;
  int b = bid >> 1, dir = bid & 1;
  int l = threadIdx.x;
  int c = l & 31;
  const float* rk_g = dir ? rkB : rkF;
  const float* bias = dir ? bB : bF;
  const float* xp_g = xproj + dir * (KK * G3);
  int len = lengths[b];

#if __has_builtin(__builtin_amdgcn_permlane32_swap)
  // Discover return-order convention once (uniform): marker 1 on lanes<32,
  // 2 on lanes>=32; ret[0]==1 everywhere iff ret[0] carries lower-half values.
  auto chk = __builtin_amdgcn_permlane32_swap(
      __float_as_uint(l < 32 ? 1.f : 2.f), __float_as_uint(l < 32 ? 1.f : 2.f),
      false, false);
  bool xIsLo = (__uint_as_float(chk[0]) == 1.f);
#else
  bool xIsLo = true;
#endif
  // Column assignment so that swap-result[0] is always z, result[1] always r.
  int zrcol = (xIsLo == (l < 32)) ? c : (32 + c);

  v2f rk2[32];  // .x: zr-column coefficient, .y: h-column coefficient
#pragma unroll
  for (int i = 0; i < 32; ++i) {
    rk2[i] = (v2f){rk_g[i * G3 + zrcol], rk_g[i * G3 + 64 + c]};
  }
  float b_h = bias[G3 + 64 + c];

  // hbuf layout: [b][k][dir*32 + c]
  float* hstore = hbuf + (size_t)b * KK * 64 + dir * 32 + c;

  int pstep = dir ? -G3 : G3;
  const float* xp0 = xp_g + (size_t)(dir ? (len - 1) : 0) * G3;
  float xzr0 = xp0[zrcol], xh0 = xp0[64 + c];
  float xzr1 = 0.f, xh1 = 0.f;
  if (len > 1) { const float* x1 = xp0 + pstep; xzr1 = x1[zrcol]; xh1 = x1[64 + c]; }
  const float* xpp = xp0 + 2 * pstep;

  float hval = 0.f;
  int p = dir ? (len - 1) : 0;
  int pinc = dir ? -1 : 1;

  for (int s = 0; s < len; ++s) {
    v2f a0 = {0.f, 0.f}, a1 = {0.f, 0.f}, a2 = {0.f, 0.f}, a3 = {0.f, 0.f};
#pragma unroll
    for (int i = 0; i < 32; i += 4) {
      float h0 = __uint_as_float(__builtin_amdgcn_readlane(__float_as_uint(hval), i));
      float h1 = __uint_as_float(__builtin_amdgcn_readlane(__float_as_uint(hval), i + 1));
      float h2 = __uint_as_float(__builtin_amdgcn_readlane(__float_as_uint(hval), i + 2));
      float h3 = __uint_as_float(__builtin_amdgcn_readlane(__float_as_uint(hval), i + 3));
      a0 = __builtin_elementwise_fma((v2f){h0, h0}, rk2[i + 0], a0);
      a1 = __builtin_elementwise_fma((v2f){h1, h1}, rk2[i + 1], a1);
      a2 = __builtin_elementwise_fma((v2f){h2, h2}, rk2[i + 2], a2);
      a3 = __builtin_elementwise_fma((v2f){h3, h3}, rk2[i + 3], a3);
    }
    v2f asum = (a0 + a1) + (a2 + a3);
    float zr_pre = asum.x + xzr0;                       // bias folded into xproj
    float hh = asum.y + b_h;
    float sig = __builtin_amdgcn_rcpf(1.f + __expf(-zr_pre));
#if __has_builtin(__builtin_amdgcn_permlane32_swap)
    auto pr = __builtin_amdgcn_permlane32_swap(__float_as_uint(sig),
                                               __float_as_uint(sig), false, false);
    float z = __uint_as_float(pr[0]);
    float r = __uint_as_float(pr[1]);
#else
    float other = __shfl_xor(sig, 32, 64);
    bool mineIsZ = (zrcol < 32);
    float z = mineIsZ ? sig : other;
    float r = mineIsZ ? other : sig;
#endif
    float pre = fmaf(r, hh, xh0);
    float e2 = __expf(2.f * pre);                       // tanh = 1 - 2/(e2+1)
    float hc = fmaf(-2.f, __builtin_amdgcn_rcpf(e2 + 1.f), 1.f);
    hval = fmaf(z, hval - hc, hc);
    if (l < 32) hstore[(size_t)p * 64] = hval;
    xzr0 = xzr1; xh0 = xh1;
    if (s + 2 < len) { xzr1 = xpp[zrcol]; xh1 = xpp[64 + c]; xpp += pstep; }
    p += pinc;
  }
}

// ---------------- kernel 3: score (h . lw) + softmax over K per batch -------
__global__ __launch_bounds__(256) void softscore_kernel(
    const int* __restrict__ lengths, const float* __restrict__ hbuf,
    const float* __restrict__ lw, float* __restrict__ wts,
    float* __restrict__ outW) {
  int b = blockIdx.x;
  int t = threadIdx.x;
  int len = lengths[b];
  __shared__ float lwS[64];
  if (t < 64) lwS[t] = lw[t];
  __syncthreads();
  const float* hb = hbuf + (size_t)b * KK * 64;

  int k0 = t, k1 = t + 256;
  float s0 = -10000.f, s1 = -10000.f;
  if (k0 < len) {
    const float4* h4 = reinterpret_cast<const float4*>(hb + (size_t)k0 * 64);
    float acc = 0.f;
#pragma unroll
    for (int q = 0; q < 16; ++q) {
      float4 v = h4[q];
      acc = fmaf(v.x, lwS[4 * q + 0], acc);
      acc = fmaf(v.y, lwS[4 * q + 1], acc);
      acc = fmaf(v.z, lwS[4 * q + 2], acc);
      acc = fmaf(v.w, lwS[4 * q + 3], acc);
    }
    s0 = acc;
  }
  if (k1 < len) {
    const float4* h4 = reinterpret_cast<const float4*>(hb + (size_t)k1 * 64);
    float acc = 0.f;
#pragma unroll
    for (int q = 0; q < 16; ++q) {
      float4 v = h4[q];
      acc = fmaf(v.x, lwS[4 * q + 0], acc);
      acc = fmaf(v.y, lwS[4 * q + 1], acc);
      acc = fmaf(v.z, lwS[4 * q + 2], acc);
      acc = fmaf(v.w, lwS[4 * q + 3], acc);
    }
    s1 = acc;
  }

  float mx = fmaxf(s0, s1);
#pragma unroll
  for (int m = 32; m >= 1; m >>= 1) mx = fmaxf(mx, __shfl_xor(mx, m, 64));
  __shared__ float redm[4];
  __shared__ float reds[4];
  int wid = t >> 6, lane = t & 63;
  if (lane == 0) redm[wid] = mx;
  __syncthreads();
  mx = fmaxf(fmaxf(redm[0], redm[1]), fmaxf(redm[2], redm[3]));
  float e0 = expf((s0 - mx) * 10.f);  // padded -> exp(~-1e5) == 0 exactly
  float e1 = expf((s1 - mx) * 10.f);
  float sum = e0 + e1;
#pragma unroll
  for (int m = 32; m >= 1; m >>= 1) sum += __shfl_xor(sum, m, 64);
  if (lane == 0) reds[wid] = sum;
  __syncthreads();
  sum = (reds[0] + reds[1]) + (reds[2] + reds[3]);
  float inv = 1.f / sum;
  float w0 = e0 * inv, w1 = e1 * inv;
  wts[b * KK + k0] = w0;
  wts[b * KK + k1] = w1;
  outW[b * KK + k0] = w0;
  outW[b * KK + k1] = w1;
}

// ---------------- kernel 4: per-(b,d) descending sort + weighted pool -------
// grid: 64 b * 64 dtiles (16 cols each). Each wave sorts 4 columns:
// 512 elems = 64 lanes x 8 regs, s = 8*lane + r, bitonic ascending.
__global__ __launch_bounds__(256) void sortpool_kernel(
    const float* __restrict__ feat, const int* __restrict__ lengths,
    const float* __restrict__ wts, float* __restrict__ outP) {
  __shared__ float tile[KK * 16];   // 32 KB, rotation-swizzled
  __shared__ float wperm[KK];       // transposed weight layout
  int bid = blockIdx.x;
  int b = bid >> 6;
  int dt = bid & 63;
  int d0 = dt * 16;
  int t = threadIdx.x;
  int len = lengths[b];

  // stage weights (transposed: w[i] at (i&7)*64 + (i>>3) -> conflict-free read)
#pragma unroll
  for (int it = 0; it < 2; ++it) {
    int i = it * 256 + t;
    wperm[(i & 7) * 64 + (i >> 3)] = wts[b * KK + i];
  }
  // stage features: coalesced float4 reads, swizzled LDS writes
  const float4* g = reinterpret_cast<const float4*>(feat + (size_t)b * KK * ND + d0);
  int c4 = t & 3, kb = t >> 2;  // 4 float4-groups x 64 k-rows per iter
#pragma unroll
  for (int it = 0; it < 8; ++it) {
    int k = it * 64 + kb;
    float4 v = g[(size_t)k * 256 + c4];
    if (k >= len) { v.x = -10000.f; v.y = -10000.f; v.z = -10000.f; v.w = -10000.f; }
    int base = k * 16;
    int rot = (k >> 3) + (k & 7);
    tile[base + ((c4 * 4 + 0 + rot) & 15)] = v.x;
    tile[base + ((c4 * 4 + 1 + rot) & 15)] = v.y;
    tile[base + ((c4 * 4 + 2 + rot) & 15)] = v.z;
    tile[base + ((c4 * 4 + 3 + rot) & 15)] = v.w;
  }
  __syncthreads();

  int wv = t >> 6, l = t & 63;
  for (int cc = 0; cc < 4; ++cc) {
    int d = wv * 4 + cc;
    float v[8];
#pragma unroll
    for (int r = 0; r < 8; ++r) {
      int k = 8 * l + r;
      v[r] = tile[k * 16 + ((d + l + r) & 15)];
    }
    // bitonic sort ascending on s = 8*l + r
#pragma unroll
    for (int kk = 1; kk <= 9; ++kk) {
#pragma unroll
      for (int j = kk - 1; j >= 0; --j) {
        if (j >= 3) {
          int m = 1 << (j - 3);
          unsigned up = (((unsigned)l >> (kk - 3)) & 1u) ^ 1u;
          unsigned hb = ((unsigned)l >> (j - 3)) & 1u;
          bool keepmin = (up ^ hb) != 0u;
#pragma unroll
          for (int r = 0; r < 8; ++r) {
            float p = __shfl_xor(v[r], m, 64);
            v[r] = keepmin ? fminf(v[r], p) : fmaxf(v[r], p);
          }
        } else {
          int mb = 1 << j;
#pragma unroll
          for (int r = 0; r < 8; ++r) {
            if (!(r & mb)) {
              int r2 = r | mb;
              bool up = ((((l << 3) + r) >> kk) & 1) == 0;
              float lo = fminf(v[r], v[r2]);
              float hi = fmaxf(v[r], v[r2]);
              v[r] = up ? lo : hi;
              v[r2] = up ? hi : lo;
            }
          }
        }
      }
    }
    // weighted sum: ascending rank s -> descending rank jd = 511 - s
    float acc = 0.f;
#pragma unroll
    for (int r = 0; r < 8; ++r) {
      int jd = 511 - (8 * l + r);
      if (jd < len) acc = fmaf(v[r], wperm[(jd & 7) * 64 + (jd >> 3)], acc);
    }
#pragma unroll
    for (int m = 32; m >= 1; m >>= 1) acc += __shfl_xor(acc, m, 64);
    if (l == 0) outP[(size_t)b * ND + d0 + d] = acc;
  }
}

extern "C" void kernel_launch(void* const* d_in, const int* in_sizes, int n_in,
                              void* d_out, int out_size, void* d_ws, size_t ws_size,
                              hipStream_t stream) {
  const float* feat    = (const float*)d_in[0];
  const int*   lengths = (const int*)d_in[1];
  const float* kF      = (const float*)d_in[2];
  const float* rkF     = (const float*)d_in[3];
  const float* bF      = (const float*)d_in[4];
  const float* kB      = (const float*)d_in[5];
  const float* rkB     = (const float*)d_in[6];
  const float* bB      = (const float*)d_in[7];
  const float* lw      = (const float*)d_in[8];

  float* outP = (float*)d_out;                 // pooled [64,1024]
  float* outW = (float*)d_out + NB * ND;       // weights [64,512]

  float* ws    = (float*)d_ws;
  float* xproj = ws;                           // [2][512][96]
  float* hbuf  = ws + 2 * KK * G3;             // [64][512][64]  (fwd32|bwd32)
  float* wts   = hbuf + (size_t)NB * KK * 64;  // [64][512]

  xproj_kernel<<<KK, 192, 0, stream>>>(kF, bF, kB, bB, xproj);
  gru3_kernel<<<NB * 2, 64, 0, stream>>>(rkF, rkB, bF, bB, lengths, xproj, hbuf);
  softscore_kernel<<<NB, 256, 0, stream>>>(lengths, hbuf, lw, wts, outW);
  sortpool_kernel<<<NB * 64, 256, 0, stream>>>(feat, lengths, wts, outP);
}

// Round 4
// 400.078 us; speedup vs baseline: 1.4226x; 1.0004x over previous
//
#include <hip/hip_runtime.h>
#include <math.h>

#define NB 64
#define KK 512
#define ND 1024
#define NH 32
#define G3 96   // 3*H
#define DPE 32

typedef float v2f __attribute__((ext_vector_type(2)));

// ---------------- kernel 1: x-projection (pe @ kernel + bias0 + zr-part of
// bias1 folded), both dirs ----------------------------------------------------
__global__ __launch_bounds__(192) void xproj_kernel(
    const float* __restrict__ kF, const float* __restrict__ bF,
    const float* __restrict__ kB, const float* __restrict__ bB,
    float* __restrict__ xproj) {
  int k = blockIdx.x;
  int t = threadIdx.x;
  __shared__ float pe[DPE];
  if (t < DPE) {
    int j = t >> 1;
    float dv = expf((float)j * -0.57564627324851147f);  // -ln(10000)/16
    float arg = (float)k * dv;
    pe[t] = (t & 1) ? cosf(arg) : sinf(arg);
  }
  __syncthreads();
  int dir = t / G3;
  int c = t - dir * G3;
  const float* kern = dir ? kB : kF;
  const float* bias = dir ? bB : bF;
  float acc = bias[c] + (c < 64 ? bias[G3 + c] : 0.f);  // fold recurrent zr bias
#pragma unroll
  for (int i = 0; i < DPE; ++i) acc = fmaf(pe[i], kern[i * G3 + c], acc);
  xproj[dir * (KK * G3) + k * G3 + c] = acc;
}

// ---------------- kernel 2: sequential GRU, 1 wave per (b,dir) --------------
// launch_bounds(64,1): full VGPR budget so the 64 recurrent-weight floats stay
// register-resident (R3's 40-VGPR allocation forced per-step weight reloads).
// h history -> LDS (XOR-swizzled); scores computed in a parallel tail phase;
// NO global loads/stores on the per-step critical path except xproj prefetch.
__global__ __launch_bounds__(64, 1) void gru4_kernel(
    const float* __restrict__ rkF, const float* __restrict__ rkB,
    const float* __restrict__ bF, const float* __restrict__ bB,
    const float* __restrict__ lw, const int* __restrict__ lengths,
    const float* __restrict__ xproj, float* __restrict__ scoreW) {
  __shared__ float hist[KK * NH];  // 64 KB, element (k,c) at k*32 + (c^(k&31))
  int bid = blockIdx.x;
  int b = bid >> 1, dir = bid & 1;
  int l = threadIdx.x;
  int c = l & 31;
  const float* rk_g = dir ? rkB : rkF;
  const float* bias = dir ? bB : bF;
  const float* xp_g = xproj + dir * (KK * G3);
  int len = lengths[b];

#if __has_builtin(__builtin_amdgcn_permlane32_swap)
  auto chk = __builtin_amdgcn_permlane32_swap(
      __float_as_uint(l < 32 ? 1.f : 2.f), __float_as_uint(l < 32 ? 1.f : 2.f),
      false, false);
  bool xIsLo = (__uint_as_float(chk[0]) == 1.f);
#else
  bool xIsLo = true;
#endif
  // Column assignment so that swap-result[0] is always z, result[1] always r.
  int zrcol = (xIsLo == (l < 32)) ? c : (32 + c);

  v2f rk2[32];  // .x: zr-column coefficient, .y: h-column coefficient
#pragma unroll
  for (int i = 0; i < 32; ++i) {
    rk2[i] = (v2f){rk_g[i * G3 + zrcol], rk_g[i * G3 + 64 + c]};
  }
  float b_h = bias[G3 + 64 + c];

  int pstep = dir ? -G3 : G3;
  const float* xp0 = xp_g + (size_t)(dir ? (len - 1) : 0) * G3;
  float xzr0 = xp0[zrcol], xh0 = xp0[64 + c];
  float xzr1 = 0.f, xh1 = 0.f;
  if (len > 1) { const float* x1 = xp0 + pstep; xzr1 = x1[zrcol]; xh1 = x1[64 + c]; }
  const float* xpp = xp0 + 2 * pstep;

  float hval = 0.f;
  int p = dir ? (len - 1) : 0;
  int pinc = dir ? -1 : 1;

  for (int s = 0; s < len; ++s) {
    v2f a0 = {0.f, 0.f}, a1 = {0.f, 0.f}, a2 = {0.f, 0.f}, a3 = {0.f, 0.f};
#pragma unroll
    for (int i = 0; i < 32; i += 4) {
      float h0 = __uint_as_float(__builtin_amdgcn_readlane(__float_as_uint(hval), i));
      float h1 = __uint_as_float(__builtin_amdgcn_readlane(__float_as_uint(hval), i + 1));
      float h2 = __uint_as_float(__builtin_amdgcn_readlane(__float_as_uint(hval), i + 2));
      float h3 = __uint_as_float(__builtin_amdgcn_readlane(__float_as_uint(hval), i + 3));
      a0 = __builtin_elementwise_fma((v2f){h0, h0}, rk2[i + 0], a0);
      a1 = __builtin_elementwise_fma((v2f){h1, h1}, rk2[i + 1], a1);
      a2 = __builtin_elementwise_fma((v2f){h2, h2}, rk2[i + 2], a2);
      a3 = __builtin_elementwise_fma((v2f){h3, h3}, rk2[i + 3], a3);
    }
    v2f asum = (a0 + a1) + (a2 + a3);
    float zr_pre = asum.x + xzr0;                       // bias folded into xproj
    float hh = asum.y + b_h;
    float sig = __builtin_amdgcn_rcpf(1.f + __expf(-zr_pre));
#if __has_builtin(__builtin_amdgcn_permlane32_swap)
    auto pr = __builtin_amdgcn_permlane32_swap(__float_as_uint(sig),
                                               __float_as_uint(sig), false, false);
    float z = __uint_as_float(pr[0]);
    float r = __uint_as_float(pr[1]);
#else
    float other = __shfl_xor(sig, 32, 64);
    bool mineIsZ = (zrcol < 32);
    float z = mineIsZ ? sig : other;
    float r = mineIsZ ? other : sig;
#endif
    float pre = fmaf(r, hh, xh0);
    float e2 = __expf(2.f * pre);                       // tanh = 1 - 2/(e2+1)
    float hc = fmaf(-2.f, __builtin_amdgcn_rcpf(e2 + 1.f), 1.f);
    hval = fmaf(z, hval - hc, hc);
    if (l < 32) hist[p * NH + (c ^ (p & 31))] = hval;   // conflict-free, no vmcnt
    xzr0 = xzr1; xh0 = xh1;
    if (s + 2 < len) { xzr1 = xpp[zrcol]; xh1 = xpp[64 + c]; xpp += pstep; }
    p += pinc;
  }
  __syncthreads();

  // tail: scores for all k in parallel (lane l handles k = it*64 + l)
  float lws[NH];
#pragma unroll
  for (int i = 0; i < NH; ++i) lws[i] = lw[dir * NH + i];
  float* so = scoreW + (size_t)(dir * NB + b) * KK;
#pragma unroll
  for (int it = 0; it < 8; ++it) {
    int k = it * 64 + l;
    if (k < len) {
      float acc = 0.f;
#pragma unroll
      for (int i = 0; i < NH; ++i)
        acc = fmaf(hist[k * NH + (i ^ (k & 31))], lws[i], acc);
      so[k] = acc;
    }
  }
}

// ---------------- kernel 3: softmax over K per batch ------------------------
__global__ __launch_bounds__(256) void softmax_kernel(
    const int* __restrict__ lengths, const float* __restrict__ scoreW,
    float* __restrict__ wts, float* __restrict__ outW) {
  int b = blockIdx.x;
  int t = threadIdx.x;
  int len = lengths[b];
  const float* sf = scoreW + b * KK;
  const float* sb = scoreW + (NB + b) * KK;
  int k0 = t, k1 = t + 256;
  float s0 = -10000.f, s1 = -10000.f;
  if (k0 < len) s0 = sf[k0] + sb[k0];
  if (k1 < len) s1 = sf[k1] + sb[k1];
  float mx = fmaxf(s0, s1);
#pragma unroll
  for (int m = 32; m >= 1; m >>= 1) mx = fmaxf(mx, __shfl_xor(mx, m, 64));
  __shared__ float redm[4];
  __shared__ float reds[4];
  int wid = t >> 6, lane = t & 63;
  if (lane == 0) redm[wid] = mx;
  __syncthreads();
  mx = fmaxf(fmaxf(redm[0], redm[1]), fmaxf(redm[2], redm[3]));
  float e0 = expf((s0 - mx) * 10.f);  // padded -> exp(~-1e5) == 0 exactly
  float e1 = expf((s1 - mx) * 10.f);
  float sum = e0 + e1;
#pragma unroll
  for (int m = 32; m >= 1; m >>= 1) sum += __shfl_xor(sum, m, 64);
  if (lane == 0) reds[wid] = sum;
  __syncthreads();
  sum = (reds[0] + reds[1]) + (reds[2] + reds[3]);
  float inv = 1.f / sum;
  float w0 = e0 * inv, w1 = e1 * inv;
  wts[b * KK + k0] = w0;
  wts[b * KK + k1] = w1;
  outW[b * KK + k0] = w0;
  outW[b * KK + k1] = w1;
}

// ---------------- kernel 4: per-(b,d) descending sort + weighted pool -------
// grid: 64 b * 64 dtiles (16 cols each). Each wave sorts 4 columns:
// 512 elems = 64 lanes x 8 regs, s = 8*lane + r, bitonic ascending.
__global__ __launch_bounds__(256) void sortpool_kernel(
    const float* __restrict__ feat, const int* __restrict__ lengths,
    const float* __restrict__ wts, float* __restrict__ outP) {
  __shared__ float tile[KK * 16];   // 32 KB, rotation-swizzled
  __shared__ float wperm[KK];       // transposed weight layout
  int bid = blockIdx.x;
  int b = bid >> 6;
  int dt = bid & 63;
  int d0 = dt * 16;
  int t = threadIdx.x;
  int len = lengths[b];

  // stage weights (transposed: w[i] at (i&7)*64 + (i>>3) -> conflict-free read)
#pragma unroll
  for (int it = 0; it < 2; ++it) {
    int i = it * 256 + t;
    wperm[(i & 7) * 64 + (i >> 3)] = wts[b * KK + i];
  }
  // stage features: coalesced float4 reads, swizzled LDS writes
  const float4* g = reinterpret_cast<const float4*>(feat + (size_t)b * KK * ND + d0);
  int c4 = t & 3, kb = t >> 2;  // 4 float4-groups x 64 k-rows per iter
#pragma unroll
  for (int it = 0; it < 8; ++it) {
    int k = it * 64 + kb;
    float4 v = g[(size_t)k * 256 + c4];
    if (k >= len) { v.x = -10000.f; v.y = -10000.f; v.z = -10000.f; v.w = -10000.f; }
    int base = k * 16;
    int rot = (k >> 3) + (k & 7);
    tile[base + ((c4 * 4 + 0 + rot) & 15)] = v.x;
    tile[base + ((c4 * 4 + 1 + rot) & 15)] = v.y;
    tile[base + ((c4 * 4 + 2 + rot) & 15)] = v.z;
    tile[base + ((c4 * 4 + 3 + rot) & 15)] = v.w;
  }
  __syncthreads();

  int wv = t >> 6, l = t & 63;
  for (int cc = 0; cc < 4; ++cc) {
    int d = wv * 4 + cc;
    float v[8];
#pragma unroll
    for (int r = 0; r < 8; ++r) {
      int k = 8 * l + r;
      v[r] = tile[k * 16 + ((d + l + r) & 15)];
    }
    // bitonic sort ascending on s = 8*l + r
#pragma unroll
    for (int kk = 1; kk <= 9; ++kk) {
#pragma unroll
      for (int j = kk - 1; j >= 0; --j) {
        if (j >= 3) {
          int m = 1 << (j - 3);
          unsigned up = (((unsigned)l >> (kk - 3)) & 1u) ^ 1u;
          unsigned hb = ((unsigned)l >> (j - 3)) & 1u;
          bool keepmin = (up ^ hb) != 0u;
#pragma unroll
          for (int r = 0; r < 8; ++r) {
            float p = __shfl_xor(v[r], m, 64);
            v[r] = keepmin ? fminf(v[r], p) : fmaxf(v[r], p);
          }
        } else {
          int mb = 1 << j;
#pragma unroll
          for (int r = 0; r < 8; ++r) {
            if (!(r & mb)) {
              int r2 = r | mb;
              bool up = ((((l << 3) + r) >> kk) & 1) == 0;
              float lo = fminf(v[r], v[r2]);
              float hi = fmaxf(v[r], v[r2]);
              v[r] = up ? lo : hi;
              v[r2] = up ? hi : lo;
            }
          }
        }
      }
    }
    // weighted sum: ascending rank s -> descending rank jd = 511 - s
    float acc = 0.f;
#pragma unroll
    for (int r = 0; r < 8; ++r) {
      int jd = 511 - (8 * l + r);
      if (jd < len) acc = fmaf(v[r], wperm[(jd & 7) * 64 + (jd >> 3)], acc);
    }
#pragma unroll
    for (int m = 32; m >= 1; m >>= 1) acc += __shfl_xor(acc, m, 64);
    if (l == 0) outP[(size_t)b * ND + d0 + d] = acc;
  }
}

extern "C" void kernel_launch(void* const* d_in, const int* in_sizes, int n_in,
                              void* d_out, int out_size, void* d_ws, size_t ws_size,
                              hipStream_t stream) {
  const float* feat    = (const float*)d_in[0];
  const int*   lengths = (const int*)d_in[1];
  const float* kF      = (const float*)d_in[2];
  const float* rkF     = (const float*)d_in[3];
  const float* bF      = (const float*)d_in[4];
  const float* kB      = (const float*)d_in[5];
  const float* rkB     = (const float*)d_in[6];
  const float* bB      = (const float*)d_in[7];
  const float* lw      = (const float*)d_in[8];

  float* outP = (float*)d_out;                 // pooled [64,1024]
  float* outW = (float*)d_out + NB * ND;       // weights [64,512]

  float* ws     = (float*)d_ws;
  float* xproj  = ws;                          // [2][512][96]
  float* scoreW = ws + 2 * KK * G3;            // [2][64][512]
  float* wts    = scoreW + 2 * NB * KK;        // [64][512]

  xproj_kernel<<<KK, 192, 0, stream>>>(kF, bF, kB, bB, xproj);
  gru4_kernel<<<NB * 2, 64, 0, stream>>>(rkF, rkB, bF, bB, lw, lengths, xproj, scoreW);
  softmax_kernel<<<NB, 256, 0, stream>>>(lengths, scoreW, wts, outW);
  sortpool_kernel<<<NB * 64, 256, 0, stream>>>(feat, lengths, wts, outP);
}

// Round 5
// 295.646 us; speedup vs baseline: 1.9251x; 1.3532x over previous
//
#include <hip/hip_runtime.h>
#include <math.h>

#define NB 64
#define KK 512
#define ND 1024
#define NH 32
#define G3 96   // 3*H
#define DPE 32

typedef float v2f __attribute__((ext_vector_type(2)));

// ---------------- kernel 1: x-projection (pe @ kernel + bias0 + zr-part of
// bias1 folded), both dirs ----------------------------------------------------
__global__ __launch_bounds__(192) void xproj_kernel(
    const float* __restrict__ kF, const float* __restrict__ bF,
    const float* __restrict__ kB, const float* __restrict__ bB,
    float* __restrict__ xproj) {
  int k = blockIdx.x;
  int t = threadIdx.x;
  __shared__ float pe[DPE];
  if (t < DPE) {
    int j = t >> 1;
    float dv = expf((float)j * -0.57564627324851147f);  // -ln(10000)/16
    float arg = (float)k * dv;
    pe[t] = (t & 1) ? cosf(arg) : sinf(arg);
  }
  __syncthreads();
  int dir = t / G3;
  int c = t - dir * G3;
  const float* kern = dir ? kB : kF;
  const float* bias = dir ? bB : bF;
  float acc = bias[c] + (c < 64 ? bias[G3 + c] : 0.f);  // fold recurrent zr bias
#pragma unroll
  for (int i = 0; i < DPE; ++i) acc = fmaf(pe[i], kern[i * G3 + c], acc);
  xproj[dir * (KK * G3) + k * G3 + c] = acc;
}

// ---------------- kernel 2: sequential GRU, 1 wave per (b,dir) --------------
// launch_bounds(64,1): full VGPR budget, recurrent weights register-resident.
// 8-deep register ring for xproj prefetch (hand-unrolled: static indices only)
// so ~16 loads stay in flight and cross-XCD/HBM latency (~900cy) is covered by
// ~8 steps of slack. h history -> LDS; scores computed in a parallel tail.
__global__ __launch_bounds__(64, 1) void gru5_kernel(
    const float* __restrict__ rkF, const float* __restrict__ rkB,
    const float* __restrict__ bF, const float* __restrict__ bB,
    const float* __restrict__ lw, const int* __restrict__ lengths,
    const float* __restrict__ xproj, float* __restrict__ scoreW) {
  __shared__ float hist[KK * NH];  // 64 KB, element (k,c) at k*32 + (c^(k&31))
  int bid = blockIdx.x;
  int b = bid >> 1, dir = bid & 1;
  int l = threadIdx.x;
  int c = l & 31;
  const float* rk_g = dir ? rkB : rkF;
  const float* bias = dir ? bB : bF;
  const float* xp_g = xproj + dir * (KK * G3);
  int len = lengths[b];

#if __has_builtin(__builtin_amdgcn_permlane32_swap)
  auto chk = __builtin_amdgcn_permlane32_swap(
      __float_as_uint(l < 32 ? 1.f : 2.f), __float_as_uint(l < 32 ? 1.f : 2.f),
      false, false);
  bool xIsLo = (__uint_as_float(chk[0]) == 1.f);
#else
  bool xIsLo = true;
#endif
  // Column assignment so that swap-result[0] is always z, result[1] always r.
  int zrcol = (xIsLo == (l < 32)) ? c : (32 + c);

  v2f rk2[32];  // .x: zr-column coefficient, .y: h-column coefficient
#pragma unroll
  for (int i = 0; i < 32; ++i) {
    rk2[i] = (v2f){rk_g[i * G3 + zrcol], rk_g[i * G3 + 64 + c]};
  }
  float b_h = bias[G3 + 64 + c];

  // prefetch ring, depth 8 (static indices via full unroll)
  float xzr[8], xh[8];
#pragma unroll
  for (int j = 0; j < 8; ++j) {
    int pn = dir ? (len - 1 - j) : j;
    pn = pn < 0 ? 0 : (pn > len - 1 ? len - 1 : pn);
    const float* rp = xp_g + (size_t)pn * G3;
    xzr[j] = rp[zrcol];
    xh[j] = rp[64 + c];
  }

  float hval = 0.f;
  for (int s0 = 0; s0 < len; s0 += 8) {
#pragma unroll
    for (int j = 0; j < 8; ++j) {
      int s = s0 + j;
      if (s < len) {
        v2f a0 = {0.f, 0.f}, a1 = {0.f, 0.f}, a2 = {0.f, 0.f}, a3 = {0.f, 0.f};
#pragma unroll
        for (int i = 0; i < 32; i += 4) {
          float h0 = __uint_as_float(__builtin_amdgcn_readlane(__float_as_uint(hval), i));
          float h1 = __uint_as_float(__builtin_amdgcn_readlane(__float_as_uint(hval), i + 1));
          float h2 = __uint_as_float(__builtin_amdgcn_readlane(__float_as_uint(hval), i + 2));
          float h3 = __uint_as_float(__builtin_amdgcn_readlane(__float_as_uint(hval), i + 3));
          a0 = __builtin_elementwise_fma((v2f){h0, h0}, rk2[i + 0], a0);
          a1 = __builtin_elementwise_fma((v2f){h1, h1}, rk2[i + 1], a1);
          a2 = __builtin_elementwise_fma((v2f){h2, h2}, rk2[i + 2], a2);
          a3 = __builtin_elementwise_fma((v2f){h3, h3}, rk2[i + 3], a3);
        }
        v2f asum = (a0 + a1) + (a2 + a3);
        float zr_pre = asum.x + xzr[j];                 // bias folded into xproj
        float hh = asum.y + b_h;
        float sig = __builtin_amdgcn_rcpf(1.f + __expf(-zr_pre));
#if __has_builtin(__builtin_amdgcn_permlane32_swap)
        auto pr = __builtin_amdgcn_permlane32_swap(__float_as_uint(sig),
                                                   __float_as_uint(sig), false, false);
        float z = __uint_as_float(pr[0]);
        float r = __uint_as_float(pr[1]);
#else
        float other = __shfl_xor(sig, 32, 64);
        bool mineIsZ = (zrcol < 32);
        float z = mineIsZ ? sig : other;
        float r = mineIsZ ? other : sig;
#endif
        float pre = fmaf(r, hh, xh[j]);
        float e2 = __expf(2.f * pre);                   // tanh = 1 - 2/(e2+1)
        float hc = fmaf(-2.f, __builtin_amdgcn_rcpf(e2 + 1.f), 1.f);
        hval = fmaf(z, hval - hc, hc);
        int p = dir ? (len - 1 - s) : s;
        if (l < 32) hist[p * NH + (c ^ (p & 31))] = hval;  // conflict-free
        // prefetch step s+8 into this ring slot (clamped row; off critical path)
        int pn = dir ? (len - 1 - (s + 8)) : (s + 8);
        pn = pn < 0 ? 0 : (pn > len - 1 ? len - 1 : pn);
        const float* rp = xp_g + (size_t)pn * G3;
        xzr[j] = rp[zrcol];
        xh[j] = rp[64 + c];
      }
    }
  }
  __syncthreads();

  // tail: scores for all k in parallel (lane l handles k = it*64 + l)
  float lws[NH];
#pragma unroll
  for (int i = 0; i < NH; ++i) lws[i] = lw[dir * NH + i];
  float* so = scoreW + (size_t)(dir * NB + b) * KK;
#pragma unroll
  for (int it = 0; it < 8; ++it) {
    int k = it * 64 + l;
    if (k < len) {
      float acc = 0.f;
#pragma unroll
      for (int i = 0; i < NH; ++i)
        acc = fmaf(hist[k * NH + (i ^ (k & 31))], lws[i], acc);
      so[k] = acc;
    }
  }
}

// ---------------- kernel 3: softmax over K per batch ------------------------
__global__ __launch_bounds__(256) void softmax_kernel(
    const int* __restrict__ lengths, const float* __restrict__ scoreW,
    float* __restrict__ wts, float* __restrict__ outW) {
  int b = blockIdx.x;
  int t = threadIdx.x;
  int len = lengths[b];
  const float* sf = scoreW + b * KK;
  const float* sb = scoreW + (NB + b) * KK;
  int k0 = t, k1 = t + 256;
  float s0 = -10000.f, s1 = -10000.f;
  if (k0 < len) s0 = sf[k0] + sb[k0];
  if (k1 < len) s1 = sf[k1] + sb[k1];
  float mx = fmaxf(s0, s1);
#pragma unroll
  for (int m = 32; m >= 1; m >>= 1) mx = fmaxf(mx, __shfl_xor(mx, m, 64));
  __shared__ float redm[4];
  __shared__ float reds[4];
  int wid = t >> 6, lane = t & 63;
  if (lane == 0) redm[wid] = mx;
  __syncthreads();
  mx = fmaxf(fmaxf(redm[0], redm[1]), fmaxf(redm[2], redm[3]));
  float e0 = expf((s0 - mx) * 10.f);  // padded -> exp(~-1e5) == 0 exactly
  float e1 = expf((s1 - mx) * 10.f);
  float sum = e0 + e1;
#pragma unroll
  for (int m = 32; m >= 1; m >>= 1) sum += __shfl_xor(sum, m, 64);
  if (lane == 0) reds[wid] = sum;
  __syncthreads();
  sum = (reds[0] + reds[1]) + (reds[2] + reds[3]);
  float inv = 1.f / sum;
  float w0 = e0 * inv, w1 = e1 * inv;
  wts[b * KK + k0] = w0;
  wts[b * KK + k1] = w1;
  outW[b * KK + k0] = w0;
  outW[b * KK + k1] = w1;
}

// ---------------- kernel 4: per-(b,d) descending sort + weighted pool -------
// grid: 64 b * 64 dtiles (16 cols each). Each wave sorts 4 columns:
// 512 elems = 64 lanes x 8 regs, s = 8*lane + r, bitonic ascending.
__global__ __launch_bounds__(256) void sortpool_kernel(
    const float* __restrict__ feat, const int* __restrict__ lengths,
    const float* __restrict__ wts, float* __restrict__ outP) {
  __shared__ float tile[KK * 16];   // 32 KB, rotation-swizzled
  __shared__ float wperm[KK];       // transposed weight layout
  int bid = blockIdx.x;
  int b = bid >> 6;
  int dt = bid & 63;
  int d0 = dt * 16;
  int t = threadIdx.x;
  int len = lengths[b];

  // stage weights (transposed: w[i] at (i&7)*64 + (i>>3) -> conflict-free read)
#pragma unroll
  for (int it = 0; it < 2; ++it) {
    int i = it * 256 + t;
    wperm[(i & 7) * 64 + (i >> 3)] = wts[b * KK + i];
  }
  // stage features: coalesced float4 reads, swizzled LDS writes
  const float4* g = reinterpret_cast<const float4*>(feat + (size_t)b * KK * ND + d0);
  int c4 = t & 3, kb = t >> 2;  // 4 float4-groups x 64 k-rows per iter
#pragma unroll
  for (int it = 0; it < 8; ++it) {
    int k = it * 64 + kb;
    float4 v = g[(size_t)k * 256 + c4];
    if (k >= len) { v.x = -10000.f; v.y = -10000.f; v.z = -10000.f; v.w = -10000.f; }
    int base = k * 16;
    int rot = (k >> 3) + (k & 7);
    tile[base + ((c4 * 4 + 0 + rot) & 15)] = v.x;
    tile[base + ((c4 * 4 + 1 + rot) & 15)] = v.y;
    tile[base + ((c4 * 4 + 2 + rot) & 15)] = v.z;
    tile[base + ((c4 * 4 + 3 + rot) & 15)] = v.w;
  }
  __syncthreads();

  int wv = t >> 6, l = t & 63;
  for (int cc = 0; cc < 4; ++cc) {
    int d = wv * 4 + cc;
    float v[8];
#pragma unroll
    for (int r = 0; r < 8; ++r) {
      int k = 8 * l + r;
      v[r] = tile[k * 16 + ((d + l + r) & 15)];
    }
    // bitonic sort ascending on s = 8*l + r
#pragma unroll
    for (int kk = 1; kk <= 9; ++kk) {
#pragma unroll
      for (int j = kk - 1; j >= 0; --j) {
        if (j >= 3) {
          int m = 1 << (j - 3);
          unsigned up = (((unsigned)l >> (kk - 3)) & 1u) ^ 1u;
          unsigned hb = ((unsigned)l >> (j - 3)) & 1u;
          bool keepmin = (up ^ hb) != 0u;
#pragma unroll
          for (int r = 0; r < 8; ++r) {
            float p = __shfl_xor(v[r], m, 64);
            v[r] = keepmin ? fminf(v[r], p) : fmaxf(v[r], p);
          }
        } else {
          int mb = 1 << j;
#pragma unroll
          for (int r = 0; r < 8; ++r) {
            if (!(r & mb)) {
              int r2 = r | mb;
              bool up = ((((l << 3) + r) >> kk) & 1) == 0;
              float lo = fminf(v[r], v[r2]);
              float hi = fmaxf(v[r], v[r2]);
              v[r] = up ? lo : hi;
              v[r2] = up ? hi : lo;
            }
          }
        }
      }
    }
    // weighted sum: ascending rank s -> descending rank jd = 511 - s
    float acc = 0.f;
#pragma unroll
    for (int r = 0; r < 8; ++r) {
      int jd = 511 - (8 * l + r);
      if (jd < len) acc = fmaf(v[r], wperm[(jd & 7) * 64 + (jd >> 3)], acc);
    }
#pragma unroll
    for (int m = 32; m >= 1; m >>= 1) acc += __shfl_xor(acc, m, 64);
    if (l == 0) outP[(size_t)b * ND + d0 + d] = acc;
  }
}

extern "C" void kernel_launch(void* const* d_in, const int* in_sizes, int n_in,
                              void* d_out, int out_size, void* d_ws, size_t ws_size,
                              hipStream_t stream) {
  const float* feat    = (const float*)d_in[0];
  const int*   lengths = (const int*)d_in[1];
  const float* kF      = (const float*)d_in[2];
  const float* rkF     = (const float*)d_in[3];
  const float* bF      = (const float*)d_in[4];
  const float* kB      = (const float*)d_in[5];
  const float* rkB     = (const float*)d_in[6];
  const float* bB      = (const float*)d_in[7];
  const float* lw      = (const float*)d_in[8];

  float* outP = (float*)d_out;                 // pooled [64,1024]
  float* outW = (float*)d_out + NB * ND;       // weights [64,512]

  float* ws     = (float*)d_ws;
  float* xproj  = ws;                          // [2][512][96]
  float* scoreW = ws + 2 * KK * G3;            // [2][64][512]
  float* wts    = scoreW + 2 * NB * KK;        // [64][512]

  xproj_kernel<<<KK, 192, 0, stream>>>(kF, bF, kB, bB, xproj);
  gru5_kernel<<<NB * 2, 64, 0, stream>>>(rkF, rkB, bF, bB, lw, lengths, xproj, scoreW);
  softmax_kernel<<<NB, 256, 0, stream>>>(lengths, scoreW, wts, outW);
  sortpool_kernel<<<NB * 64, 256, 0, stream>>>(feat, lengths, wts, outP);
}